// Round 1
// baseline (476.314 us; speedup 1.0000x reference)
//
#include <hip/hip_runtime.h>
#include <math.h>

namespace {
constexpr int Tn = 128, Bn = 16, An = 32, OBS = 256, Kh = 3, NACT = 9, HID = 32;
constexpr int TBA = Tn * Bn * An;   // 65536 rows through the MLP
constexpr int BA  = Bn * An;        // 512 LSTM sequences
constexpr int OUT_LP  = TBA * Kh;         // 196608: logprobs start
constexpr int OUT_ENT = TBA * Kh + TBA;   // 262144: entropies start
}

// ---------------------------------------------------------------------------
// GEMM building blocks for the fused MLP kernel.
// Block tile: 64 rows x (up to 128) outs. Thread tile: 8 rows x NOI outs
// (outs strided by 32 so b128 LDS reads of the weight tile are only the
// inherent 4-way granule aliasing, and all stores are lane-consecutive).
// Weight tiles staged in LDS as [o][68] (68-float row stride keeps b128
// writes ~2-way and rows 16B-aligned).
// ---------------------------------------------------------------------------
template<int NOI, int XSTR>
__device__ __forceinline__ void gemm_step(const float* __restrict__ xsrc,
                                          const float* __restrict__ wtile,
                                          int rg, int og, float acc[8][4])
{
#pragma unroll
  for (int k4 = 0; k4 < 16; ++k4) {
    float4 wv[NOI];
#pragma unroll
    for (int oi = 0; oi < NOI; ++oi)
      wv[oi] = *(const float4*)&wtile[(og + 32*oi)*68 + k4*4];
#pragma unroll
    for (int rr = 0; rr < 8; ++rr) {
      float4 xv = *(const float4*)&xsrc[(rg*8 + rr)*XSTR + k4*4];
#pragma unroll
      for (int oi = 0; oi < NOI; ++oi) {
        acc[rr][oi] = fmaf(xv.x, wv[oi].x, acc[rr][oi]);
        acc[rr][oi] = fmaf(xv.y, wv[oi].y, acc[rr][oi]);
        acc[rr][oi] = fmaf(xv.z, wv[oi].z, acc[rr][oi]);
        acc[rr][oi] = fmaf(xv.w, wv[oi].w, acc[rr][oi]);
      }
    }
  }
}

template<int NO, int WSTR>   // NO = weight-tile rows (64/128), WSTR = global row stride
__device__ __forceinline__ void load_wtile(const float* __restrict__ Wg, int kofs,
                                           float* __restrict__ wtile, int tid)
{
#pragma unroll
  for (int it = 0; it < (NO*16)/256; ++it) {
    int idx = tid + it*256;
    int o = idx >> 4, k4 = idx & 15;
    float4 v = *(const float4*)&Wg[(size_t)o*WSTR + kofs + k4*4];
    *(float4*)&wtile[o*68 + k4*4] = v;
  }
}

// Fused MLP trunk + LSTM input projection:
// z = tanh(tanh(x@W1'+b1)@W2'+b2)@W3'+b3 ; G1 = z@Wih' + bih + bhh
__global__ __launch_bounds__(256) void mlp_kernel(
    const float* __restrict__ x,
    const float* __restrict__ W1, const float* __restrict__ b1,
    const float* __restrict__ W2, const float* __restrict__ b2,
    const float* __restrict__ W3, const float* __restrict__ b3,
    const float* __restrict__ Wih, const float* __restrict__ bih,
    const float* __restrict__ bhh, float* __restrict__ G1)
{
  __shared__ __align__(16) float xs[64*64];     // x k-tile; reused for z[64][64]
  __shared__ __align__(16) float wt[128*68];    // weight tile
  __shared__ __align__(16) float actA[64*128];
  __shared__ __align__(16) float actB[64*128];
  const int tid = threadIdx.x;
  const int og = tid & 31;
  const int rg = tid >> 5;
  const int R0 = blockIdx.x * 64;
  float acc[8][4];

  // ---- layer 1: 256 -> 128, tanh (4 k-tiles of 64) ----
#pragma unroll
  for (int rr = 0; rr < 8; ++rr)
#pragma unroll
    for (int oi = 0; oi < 4; ++oi) acc[rr][oi] = 0.f;
  for (int kt = 0; kt < 4; ++kt) {
#pragma unroll
    for (int it = 0; it < 4; ++it) {            // stage x tile [64][64]
      int idx = tid + it*256;
      int r = idx >> 4, k4 = idx & 15;
      *(float4*)&xs[r*64 + k4*4] =
          *(const float4*)&x[(size_t)(R0 + r)*OBS + kt*64 + k4*4];
    }
    load_wtile<128, 256>(W1, kt*64, wt, tid);
    __syncthreads();
    gemm_step<4, 64>(xs, wt, rg, og, acc);
    __syncthreads();
  }
#pragma unroll
  for (int rr = 0; rr < 8; ++rr)
#pragma unroll
    for (int oi = 0; oi < 4; ++oi)
      actA[(rg*8+rr)*128 + og + 32*oi] = tanhf(acc[rr][oi] + b1[og + 32*oi]);

  // ---- layer 2: 128 -> 128, tanh (2 k-tiles) ----
#pragma unroll
  for (int rr = 0; rr < 8; ++rr)
#pragma unroll
    for (int oi = 0; oi < 4; ++oi) acc[rr][oi] = 0.f;
  for (int kt = 0; kt < 2; ++kt) {
    load_wtile<128, 128>(W2, kt*64, wt, tid);
    __syncthreads();                            // also publishes actA / prev compute
    gemm_step<4, 128>(actA + kt*64, wt, rg, og, acc);
    __syncthreads();
  }
#pragma unroll
  for (int rr = 0; rr < 8; ++rr)
#pragma unroll
    for (int oi = 0; oi < 4; ++oi)
      actB[(rg*8+rr)*128 + og + 32*oi] = tanhf(acc[rr][oi] + b2[og + 32*oi]);

  // ---- layer 3: 128 -> 64, linear (2 k-tiles) ----
#pragma unroll
  for (int rr = 0; rr < 8; ++rr)
#pragma unroll
    for (int oi = 0; oi < 4; ++oi) acc[rr][oi] = 0.f;
  for (int kt = 0; kt < 2; ++kt) {
    load_wtile<64, 128>(W3, kt*64, wt, tid);
    __syncthreads();
    gemm_step<2, 128>(actB + kt*64, wt, rg, og, acc);
    __syncthreads();
  }
#pragma unroll
  for (int rr = 0; rr < 8; ++rr)
#pragma unroll
    for (int oi = 0; oi < 2; ++oi)
      xs[(rg*8+rr)*64 + og + 32*oi] = acc[rr][oi] + b3[og + 32*oi];  // z tile

  // ---- layer 4: z(64) -> 128 gate inputs: z@Wih' + bih + bhh ----
#pragma unroll
  for (int rr = 0; rr < 8; ++rr)
#pragma unroll
    for (int oi = 0; oi < 4; ++oi) acc[rr][oi] = 0.f;
  load_wtile<128, 64>(Wih, 0, wt, tid);
  __syncthreads();                              // publishes z writes + wt
  gemm_step<4, 64>(xs, wt, rg, og, acc);
#pragma unroll
  for (int rr = 0; rr < 8; ++rr)
#pragma unroll
    for (int oi = 0; oi < 4; ++oi) {
      int o = og + 32*oi;
      G1[(size_t)(R0 + rg*8 + rr)*128 + o] = acc[rr][oi] + bih[o] + bhh[o];
    }
}

// ---------------------------------------------------------------------------
// LSTM scan. 2 rows/block x 32 threads/row (1 wave). Thread j owns hidden
// unit j: computes gates j, j+32, j+64, j+96, so c/h stay in registers.
// Whh rows for those 4 gates live in 128 VGPRs. h broadcast via LDS.
// G1 gate inputs for step t+1 prefetched during step t's compute.
// ---------------------------------------------------------------------------
__global__ __launch_bounds__(64) void lstm_kernel(
    const float* __restrict__ G1, const float* __restrict__ Whh,
    const int* __restrict__ done, const float* __restrict__ h0,
    const float* __restrict__ c0, float* __restrict__ Y)
{
  __shared__ __align__(16) float hs[2][32];
  const int tid = threadIdx.x;
  const int lrow = tid >> 5;
  const int j = tid & 31;
  const int row = blockIdx.x * 2 + lrow;   // 0..511
  const int b = row >> 5;                  // row / A
  float4 w[4][8];
#pragma unroll
  for (int q = 0; q < 4; ++q)
#pragma unroll
    for (int k4 = 0; k4 < 8; ++k4)
      w[q][k4] = *(const float4*)&Whh[(j + 32*q)*HID + k4*4];
  float h = h0[row*HID + j];
  float c = c0[row*HID + j];
  const float* gp = G1 + (size_t)row*128 + j;
  float gn0 = gp[0], gn1 = gp[32], gn2 = gp[64], gn3 = gp[96];
  for (int t = 0; t < Tn; ++t) {
    float m = 1.0f - (float)done[t*Bn + b];
    h *= m; c *= m;
    hs[lrow][j] = h;
    __syncthreads();
    float g0 = gn0, g1 = gn1, g2 = gn2, g3 = gn3;
    if (t < Tn - 1) {                      // prefetch next step's gate inputs
      const float* gq = G1 + ((size_t)(t+1)*BA + row)*128 + j;
      gn0 = gq[0]; gn1 = gq[32]; gn2 = gq[64]; gn3 = gq[96];
    }
#pragma unroll
    for (int k4 = 0; k4 < 8; ++k4) {
      float4 h4 = *(const float4*)&hs[lrow][k4*4];
      g0 = fmaf(w[0][k4].x, h4.x, g0); g0 = fmaf(w[0][k4].y, h4.y, g0);
      g0 = fmaf(w[0][k4].z, h4.z, g0); g0 = fmaf(w[0][k4].w, h4.w, g0);
      g1 = fmaf(w[1][k4].x, h4.x, g1); g1 = fmaf(w[1][k4].y, h4.y, g1);
      g1 = fmaf(w[1][k4].z, h4.z, g1); g1 = fmaf(w[1][k4].w, h4.w, g1);
      g2 = fmaf(w[2][k4].x, h4.x, g2); g2 = fmaf(w[2][k4].y, h4.y, g2);
      g2 = fmaf(w[2][k4].z, h4.z, g2); g2 = fmaf(w[2][k4].w, h4.w, g2);
      g3 = fmaf(w[3][k4].x, h4.x, g3); g3 = fmaf(w[3][k4].y, h4.y, g3);
      g3 = fmaf(w[3][k4].z, h4.z, g3); g3 = fmaf(w[3][k4].w, h4.w, g3);
    }
    __syncthreads();                       // protect hs before next overwrite
    float ig = 1.f / (1.f + __expf(-g0));
    float fg = 1.f / (1.f + __expf(-g1));
    float gg = tanhf(g2);
    float oo = 1.f / (1.f + __expf(-g3));
    c = fg * c + ig * gg;
    h = oo * tanhf(c);
    Y[((size_t)t*BA + row)*HID + j] = h;
  }
}

// ---------------------------------------------------------------------------
// Heads: per row, 27 logits (3 heads x 9), log-softmax, entropy, gather,
// product of chosen log-probs. One thread per row; y staged in LDS (+1 pad).
// ---------------------------------------------------------------------------
__global__ __launch_bounds__(256) void head_kernel(
    const float* __restrict__ Y, const float* __restrict__ Wh,
    const float* __restrict__ bh, const int* __restrict__ actions,
    float* __restrict__ out)
{
  __shared__ float ys[256*33];
  __shared__ __align__(16) float whs[27*32];
  __shared__ float bhs[32];
  const int tid = threadIdx.x;
  const int R0 = blockIdx.x * 256;
  for (int i = tid; i < 27*32; i += 256) whs[i] = Wh[i];
  if (tid < 27) bhs[tid] = bh[tid];
#pragma unroll
  for (int it = 0; it < 8; ++it) {
    int idx = tid + it*256;
    int r = idx >> 3, f4 = idx & 7;
    float4 v = *(const float4*)&Y[(size_t)(R0 + r)*32 + f4*4];
    ys[r*33 + f4*4 + 0] = v.x;
    ys[r*33 + f4*4 + 1] = v.y;
    ys[r*33 + f4*4 + 2] = v.z;
    ys[r*33 + f4*4 + 3] = v.w;
  }
  __syncthreads();
  float yv[32];
#pragma unroll
  for (int k = 0; k < 32; ++k) yv[k] = ys[tid*33 + k];
  float l[27];
#pragma unroll
  for (int m = 0; m < 27; ++m) {
    float a = bhs[m];
#pragma unroll
    for (int k4 = 0; k4 < 8; ++k4) {
      float4 w4 = *(const float4*)&whs[m*32 + k4*4];   // uniform -> broadcast
      a = fmaf(yv[k4*4+0], w4.x, a);
      a = fmaf(yv[k4*4+1], w4.y, a);
      a = fmaf(yv[k4*4+2], w4.z, a);
      a = fmaf(yv[k4*4+3], w4.w, a);
    }
    l[m] = a;
  }
  const int row = R0 + tid;
  float logprob = 1.0f;
#pragma unroll
  for (int kk = 0; kk < 3; ++kk) {
    float mx = l[kk*9];
#pragma unroll
    for (int n = 1; n < 9; ++n) mx = fmaxf(mx, l[kk*9+n]);
    float s = 0.f;
#pragma unroll
    for (int n = 0; n < 9; ++n) s += __expf(l[kk*9+n] - mx);
    float lse = mx + __logf(s);
    float ent = 0.f;
#pragma unroll
    for (int n = 0; n < 9; ++n) {
      float lp = l[kk*9+n] - lse;
      ent -= __expf(lp) * lp;
    }
    int a = actions[row*3 + kk];
    float alp = 0.f;
#pragma unroll
    for (int n = 0; n < 9; ++n) alp = (a == n) ? (l[kk*9+n] - lse) : alp;
    logprob *= alp;
    out[row*3 + kk] = (float)a;          // actions echoed as float
    out[OUT_ENT + row*3 + kk] = ent;
  }
  out[OUT_LP + row] = logprob;
}

extern "C" void kernel_launch(void* const* d_in, const int* in_sizes, int n_in,
                              void* d_out, int out_size, void* d_ws, size_t ws_size,
                              hipStream_t stream)
{
  const float* x       = (const float*)d_in[0];
  const int*   done    = (const int*)  d_in[1];
  const int*   actions = (const int*)  d_in[2];
  const float* W1  = (const float*)d_in[3];
  const float* b1  = (const float*)d_in[4];
  const float* W2  = (const float*)d_in[5];
  const float* b2  = (const float*)d_in[6];
  const float* W3  = (const float*)d_in[7];
  const float* b3  = (const float*)d_in[8];
  const float* Wih = (const float*)d_in[9];
  const float* Whh = (const float*)d_in[10];
  const float* bih = (const float*)d_in[11];
  const float* bhh = (const float*)d_in[12];
  const float* Wh  = (const float*)d_in[13];
  const float* bh  = (const float*)d_in[14];
  const float* h0  = (const float*)d_in[15];
  const float* c0  = (const float*)d_in[16];
  float* out = (float*)d_out;

  float* G1 = (float*)d_ws;                    // [65536][128] = 33.5 MB
  float* Y  = G1 + (size_t)TBA * 128;          // [65536][32]  =  8.4 MB

  mlp_kernel<<<TBA/64, 256, 0, stream>>>(x, W1, b1, W2, b2, W3, b3,
                                         Wih, bih, bhh, G1);
  lstm_kernel<<<BA/2, 64, 0, stream>>>(G1, Whh, done, h0, c0, Y);
  head_kernel<<<TBA/256, 256, 0, stream>>>(Y, Wh, bh, actions, out);
}

// Round 2
// 263.212 us; speedup vs baseline: 1.8096x; 1.8096x over previous
//
#include <hip/hip_runtime.h>
#include <math.h>

namespace {
constexpr int Tn = 128, Bn = 16, An = 32, OBS = 256, Kh = 3, NACT = 9, HID = 32;
constexpr int TBA = Tn * Bn * An;   // 65536 rows through the MLP
constexpr int BA  = Bn * An;        // 512 LSTM sequences
constexpr int OUT_LP  = TBA * Kh;         // 196608: logprobs start
constexpr int OUT_ENT = TBA * Kh + TBA;   // 262144: entropies start

typedef _Float16 half4v __attribute__((ext_vector_type(4)));
typedef _Float16 half8v __attribute__((ext_vector_type(8)));
typedef float    f32x4  __attribute__((ext_vector_type(4)));
}

// ---------------------------------------------------------------------------
// Fused MLP trunk + LSTM input projection, f16 MFMA (fp32 accumulate):
//   z = tanh(tanh(x@W1'+b1)@W2'+b2)@W3'+b3 ; G1 = z@Wih' + bih + bhh
// Block: 256 threads = 4 waves, 64 rows. Wave w owns rows 16w..16w+15.
// MFMA 16x16x32_f16:  A[m=lane&15][k=quad*8+j], B = W-tile row n=lane&15,
// C/D: col=lane&15, row=quad*4+reg.
// LDS tiles padded to stride 72/136 halfs -> A/B frag reads are 2-way max
// (free). fp32->fp16 conversion fused into staging.
// ---------------------------------------------------------------------------

// Stage ROWS x 64 fp32 tile (row stride WSTR) -> LDS fp16 tile (stride 72).
template<int ROWS, int WSTR>
__device__ __forceinline__ void stage_w16(const float* __restrict__ Wg, int kofs,
                                          _Float16* __restrict__ wt, int tid)
{
#pragma unroll
  for (int it = 0; it < ROWS/16; ++it) {
    int idx = tid + it*256;
    int o = idx >> 4, k4 = idx & 15;
    float4 v = *(const float4*)&Wg[(size_t)o*WSTR + kofs + k4*4];
    half4v h = { (_Float16)v.x, (_Float16)v.y, (_Float16)v.z, (_Float16)v.w };
    *(half4v*)&wt[o*72 + k4*4] = h;
  }
}

// One 64-wide K-slab of MFMA: A from xsrc (stride XSTR halfs), B from wt.
template<int NOC, int XSTR>
__device__ __forceinline__ void mfma_slab(const _Float16* __restrict__ xsrc,
                                          const _Float16* __restrict__ wt,
                                          int rA, int ln, int quad, f32x4 acc[8])
{
#pragma unroll
  for (int kc = 0; kc < 2; ++kc) {
    half8v a = *(const half8v*)&xsrc[rA*XSTR + kc*32 + quad*8];
#pragma unroll
    for (int oc = 0; oc < NOC; ++oc) {
      half8v b = *(const half8v*)&wt[(oc*16 + ln)*72 + kc*32 + quad*8];
      acc[oc] = __builtin_amdgcn_mfma_f32_16x16x32_f16(a, b, acc[oc], 0, 0, 0);
    }
  }
}

__global__ __launch_bounds__(256) void mlp_kernel(
    const float* __restrict__ x,
    const float* __restrict__ W1, const float* __restrict__ b1,
    const float* __restrict__ W2, const float* __restrict__ b2,
    const float* __restrict__ W3, const float* __restrict__ b3,
    const float* __restrict__ Wih, const float* __restrict__ bih,
    const float* __restrict__ bhh, float* __restrict__ G1)
{
  __shared__ __align__(16) _Float16 xs[64*72];    // x k-slab; reused for z
  __shared__ __align__(16) _Float16 wt[128*72];   // weight k-slab
  __shared__ __align__(16) _Float16 act[64*136];  // activations (reused in place)
  const int tid  = threadIdx.x;
  const int w    = tid >> 6;
  const int lane = tid & 63;
  const int ln   = lane & 15;
  const int quad = lane >> 4;
  const int rA   = 16*w + ln;          // tile-relative A row for this lane
  const int r0   = 16*w + quad*4;      // tile-relative first C/D row
  const int R0   = blockIdx.x * 64;
  f32x4 acc[8];

  // ---- layer 1: 256 -> 128, tanh (4 k-slabs of 64) ----
#pragma unroll
  for (int oc = 0; oc < 8; ++oc) acc[oc] = (f32x4)0.f;
  for (int kt = 0; kt < 4; ++kt) {
#pragma unroll
    for (int it = 0; it < 4; ++it) {           // stage x slab [64][64] -> fp16
      int idx = tid + it*256;
      int r = idx >> 4, k4 = idx & 15;
      float4 v = *(const float4*)&x[(size_t)(R0 + r)*OBS + kt*64 + k4*4];
      half4v h = { (_Float16)v.x, (_Float16)v.y, (_Float16)v.z, (_Float16)v.w };
      *(half4v*)&xs[r*72 + k4*4] = h;
    }
    stage_w16<128, 256>(W1, kt*64, wt, tid);
    __syncthreads();
    mfma_slab<8, 72>(xs, wt, rA, ln, quad, acc);
    __syncthreads();
  }
#pragma unroll
  for (int oc = 0; oc < 8; ++oc) {
    int o = oc*16 + ln;
    float bv = b1[o];
#pragma unroll
    for (int r = 0; r < 4; ++r)
      act[(r0 + r)*136 + o] = (_Float16)tanhf(acc[oc][r] + bv);
  }

  // ---- layer 2: 128 -> 128, tanh (2 k-slabs, A straight from act LDS) ----
#pragma unroll
  for (int oc = 0; oc < 8; ++oc) acc[oc] = (f32x4)0.f;
  for (int kt = 0; kt < 2; ++kt) {
    stage_w16<128, 128>(W2, kt*64, wt, tid);
    __syncthreads();                            // publishes act writes + wt
    mfma_slab<8, 136>(act + kt*64, wt, rA, ln, quad, acc);
    __syncthreads();
  }
#pragma unroll
  for (int oc = 0; oc < 8; ++oc) {              // overwrite act in place
    int o = oc*16 + ln;
    float bv = b2[o];
#pragma unroll
    for (int r = 0; r < 4; ++r)
      act[(r0 + r)*136 + o] = (_Float16)tanhf(acc[oc][r] + bv);
  }

  // ---- layer 3: 128 -> 64, linear -> z into xs buffer ----
#pragma unroll
  for (int oc = 0; oc < 4; ++oc) acc[oc] = (f32x4)0.f;
  for (int kt = 0; kt < 2; ++kt) {
    stage_w16<64, 128>(W3, kt*64, wt, tid);
    __syncthreads();
    mfma_slab<4, 136>(act + kt*64, wt, rA, ln, quad, acc);
    __syncthreads();
  }
#pragma unroll
  for (int oc = 0; oc < 4; ++oc) {
    int o = oc*16 + ln;
    float bv = b3[o];
#pragma unroll
    for (int r = 0; r < 4; ++r)
      xs[(r0 + r)*72 + o] = (_Float16)(acc[oc][r] + bv);
  }

  // ---- layer 4: z(64) -> 128 gate inputs: z@Wih' + bih + bhh ----
#pragma unroll
  for (int oc = 0; oc < 8; ++oc) acc[oc] = (f32x4)0.f;
  stage_w16<128, 64>(Wih, 0, wt, tid);
  __syncthreads();                              // publishes z writes + wt
  mfma_slab<8, 72>(xs, wt, rA, ln, quad, acc);
#pragma unroll
  for (int oc = 0; oc < 8; ++oc) {
    int o = oc*16 + ln;
    float badd = bih[o] + bhh[o];
#pragma unroll
    for (int r = 0; r < 4; ++r)
      G1[(size_t)(R0 + r0 + r)*128 + o] = acc[oc][r] + badd;
  }
}

// ---------------------------------------------------------------------------
// LSTM scan. 2 rows/block x 32 threads/row (1 wave). Thread j owns hidden
// unit j: computes gates j, j+32, j+64, j+96, so c/h stay in registers.
// Whh rows for those 4 gates live in 128 VGPRs. h broadcast via LDS.
// G1 gate inputs for step t+1 prefetched during step t's compute.
// ---------------------------------------------------------------------------
__global__ __launch_bounds__(64) void lstm_kernel(
    const float* __restrict__ G1, const float* __restrict__ Whh,
    const int* __restrict__ done, const float* __restrict__ h0,
    const float* __restrict__ c0, float* __restrict__ Y)
{
  __shared__ __align__(16) float hs[2][32];
  const int tid = threadIdx.x;
  const int lrow = tid >> 5;
  const int j = tid & 31;
  const int row = blockIdx.x * 2 + lrow;   // 0..511
  const int b = row >> 5;                  // row / A
  float4 w[4][8];
#pragma unroll
  for (int q = 0; q < 4; ++q)
#pragma unroll
    for (int k4 = 0; k4 < 8; ++k4)
      w[q][k4] = *(const float4*)&Whh[(j + 32*q)*HID + k4*4];
  float h = h0[row*HID + j];
  float c = c0[row*HID + j];
  const float* gp = G1 + (size_t)row*128 + j;
  float gn0 = gp[0], gn1 = gp[32], gn2 = gp[64], gn3 = gp[96];
  for (int t = 0; t < Tn; ++t) {
    float m = 1.0f - (float)done[t*Bn + b];
    h *= m; c *= m;
    hs[lrow][j] = h;
    __syncthreads();
    float g0 = gn0, g1 = gn1, g2 = gn2, g3 = gn3;
    if (t < Tn - 1) {                      // prefetch next step's gate inputs
      const float* gq = G1 + ((size_t)(t+1)*BA + row)*128 + j;
      gn0 = gq[0]; gn1 = gq[32]; gn2 = gq[64]; gn3 = gq[96];
    }
#pragma unroll
    for (int k4 = 0; k4 < 8; ++k4) {
      float4 h4 = *(const float4*)&hs[lrow][k4*4];
      g0 = fmaf(w[0][k4].x, h4.x, g0); g0 = fmaf(w[0][k4].y, h4.y, g0);
      g0 = fmaf(w[0][k4].z, h4.z, g0); g0 = fmaf(w[0][k4].w, h4.w, g0);
      g1 = fmaf(w[1][k4].x, h4.x, g1); g1 = fmaf(w[1][k4].y, h4.y, g1);
      g1 = fmaf(w[1][k4].z, h4.z, g1); g1 = fmaf(w[1][k4].w, h4.w, g1);
      g2 = fmaf(w[2][k4].x, h4.x, g2); g2 = fmaf(w[2][k4].y, h4.y, g2);
      g2 = fmaf(w[2][k4].z, h4.z, g2); g2 = fmaf(w[2][k4].w, h4.w, g2);
      g3 = fmaf(w[3][k4].x, h4.x, g3); g3 = fmaf(w[3][k4].y, h4.y, g3);
      g3 = fmaf(w[3][k4].z, h4.z, g3); g3 = fmaf(w[3][k4].w, h4.w, g3);
    }
    __syncthreads();                       // protect hs before next overwrite
    float ig = 1.f / (1.f + __expf(-g0));
    float fg = 1.f / (1.f + __expf(-g1));
    float gg = tanhf(g2);
    float oo = 1.f / (1.f + __expf(-g3));
    c = fg * c + ig * gg;
    h = oo * tanhf(c);
    Y[((size_t)t*BA + row)*HID + j] = h;
  }
}

// ---------------------------------------------------------------------------
// Heads: per row, 27 logits (3 heads x 9), log-softmax, entropy, gather,
// product of chosen log-probs. One thread per row; y staged in LDS (+1 pad).
// ---------------------------------------------------------------------------
__global__ __launch_bounds__(256) void head_kernel(
    const float* __restrict__ Y, const float* __restrict__ Wh,
    const float* __restrict__ bh, const int* __restrict__ actions,
    float* __restrict__ out)
{
  __shared__ float ys[256*33];
  __shared__ __align__(16) float whs[27*32];
  __shared__ float bhs[32];
  const int tid = threadIdx.x;
  const int R0 = blockIdx.x * 256;
  for (int i = tid; i < 27*32; i += 256) whs[i] = Wh[i];
  if (tid < 27) bhs[tid] = bh[tid];
#pragma unroll
  for (int it = 0; it < 8; ++it) {
    int idx = tid + it*256;
    int r = idx >> 3, f4 = idx & 7;
    float4 v = *(const float4*)&Y[(size_t)(R0 + r)*32 + f4*4];
    ys[r*33 + f4*4 + 0] = v.x;
    ys[r*33 + f4*4 + 1] = v.y;
    ys[r*33 + f4*4 + 2] = v.z;
    ys[r*33 + f4*4 + 3] = v.w;
  }
  __syncthreads();
  float yv[32];
#pragma unroll
  for (int k = 0; k < 32; ++k) yv[k] = ys[tid*33 + k];
  float l[27];
#pragma unroll
  for (int m = 0; m < 27; ++m) {
    float a = bhs[m];
#pragma unroll
    for (int k4 = 0; k4 < 8; ++k4) {
      float4 w4 = *(const float4*)&whs[m*32 + k4*4];   // uniform -> broadcast
      a = fmaf(yv[k4*4+0], w4.x, a);
      a = fmaf(yv[k4*4+1], w4.y, a);
      a = fmaf(yv[k4*4+2], w4.z, a);
      a = fmaf(yv[k4*4+3], w4.w, a);
    }
    l[m] = a;
  }
  const int row = R0 + tid;
  float logprob = 1.0f;
#pragma unroll
  for (int kk = 0; kk < 3; ++kk) {
    float mx = l[kk*9];
#pragma unroll
    for (int n = 1; n < 9; ++n) mx = fmaxf(mx, l[kk*9+n]);
    float s = 0.f;
#pragma unroll
    for (int n = 0; n < 9; ++n) s += __expf(l[kk*9+n] - mx);
    float lse = mx + __logf(s);
    float ent = 0.f;
#pragma unroll
    for (int n = 0; n < 9; ++n) {
      float lp = l[kk*9+n] - lse;
      ent -= __expf(lp) * lp;
    }
    int a = actions[row*3 + kk];
    float alp = 0.f;
#pragma unroll
    for (int n = 0; n < 9; ++n) alp = (a == n) ? (l[kk*9+n] - lse) : alp;
    logprob *= alp;
    out[row*3 + kk] = (float)a;          // actions echoed as float
    out[OUT_ENT + row*3 + kk] = ent;
  }
  out[OUT_LP + row] = logprob;
}

extern "C" void kernel_launch(void* const* d_in, const int* in_sizes, int n_in,
                              void* d_out, int out_size, void* d_ws, size_t ws_size,
                              hipStream_t stream)
{
  const float* x       = (const float*)d_in[0];
  const int*   done    = (const int*)  d_in[1];
  const int*   actions = (const int*)  d_in[2];
  const float* W1  = (const float*)d_in[3];
  const float* b1  = (const float*)d_in[4];
  const float* W2  = (const float*)d_in[5];
  const float* b2  = (const float*)d_in[6];
  const float* W3  = (const float*)d_in[7];
  const float* b3  = (const float*)d_in[8];
  const float* Wih = (const float*)d_in[9];
  const float* Whh = (const float*)d_in[10];
  const float* bih = (const float*)d_in[11];
  const float* bhh = (const float*)d_in[12];
  const float* Wh  = (const float*)d_in[13];
  const float* bh  = (const float*)d_in[14];
  const float* h0  = (const float*)d_in[15];
  const float* c0  = (const float*)d_in[16];
  float* out = (float*)d_out;

  float* G1 = (float*)d_ws;                    // [65536][128] = 33.5 MB
  float* Y  = G1 + (size_t)TBA * 128;          // [65536][32]  =  8.4 MB

  mlp_kernel<<<TBA/64, 256, 0, stream>>>(x, W1, b1, W2, b2, W3, b3,
                                         Wih, bih, bhh, G1);
  lstm_kernel<<<BA/2, 64, 0, stream>>>(G1, Whh, done, h0, c0, Y);
  head_kernel<<<TBA/256, 256, 0, stream>>>(Y, Wh, bh, actions, out);
}

// Round 3
// 237.281 us; speedup vs baseline: 2.0074x; 1.1093x over previous
//
#include <hip/hip_runtime.h>
#include <math.h>

namespace {
constexpr int Tn = 128, Bn = 16, An = 32, OBS = 256, Kh = 3, NACT = 9, HID = 32;
constexpr int TBA = Tn * Bn * An;   // 65536 rows through the MLP
constexpr int BA  = Bn * An;        // 512 LSTM sequences
constexpr int OUT_LP  = TBA * Kh;         // 196608: logprobs start
constexpr int OUT_ENT = TBA * Kh + TBA;   // 262144: entropies start

typedef _Float16 half4v __attribute__((ext_vector_type(4)));
typedef _Float16 half8v __attribute__((ext_vector_type(8)));
typedef float    f32x4  __attribute__((ext_vector_type(4)));
}

__device__ __forceinline__ float fast_sig(float x) {
  return __builtin_amdgcn_rcpf(1.f + __expf(-x));
}
__device__ __forceinline__ float fast_tanh(float x) {
  float xc = fminf(fmaxf(x, -10.f), 10.f);      // e^20 safe, tanh saturated
  float e = __expf(2.f * xc);
  return (e - 1.f) * __builtin_amdgcn_rcpf(e + 1.f);
}

// ---------------------------------------------------------------------------
// Fused MLP trunk + LSTM input projection, f16 MFMA (fp32 accumulate):
//   z = tanh(tanh(x@W1'+b1)@W2'+b2)@W3'+b3 ; G1 = z@Wih' + bih + bhh
// ---------------------------------------------------------------------------
template<int ROWS, int WSTR>
__device__ __forceinline__ void stage_w16(const float* __restrict__ Wg, int kofs,
                                          _Float16* __restrict__ wt, int tid)
{
#pragma unroll
  for (int it = 0; it < ROWS/16; ++it) {
    int idx = tid + it*256;
    int o = idx >> 4, k4 = idx & 15;
    float4 v = *(const float4*)&Wg[(size_t)o*WSTR + kofs + k4*4];
    half4v h = { (_Float16)v.x, (_Float16)v.y, (_Float16)v.z, (_Float16)v.w };
    *(half4v*)&wt[o*72 + k4*4] = h;
  }
}

template<int NOC, int XSTR>
__device__ __forceinline__ void mfma_slab(const _Float16* __restrict__ xsrc,
                                          const _Float16* __restrict__ wt,
                                          int rA, int ln, int quad, f32x4 acc[8])
{
#pragma unroll
  for (int kc = 0; kc < 2; ++kc) {
    half8v a = *(const half8v*)&xsrc[rA*XSTR + kc*32 + quad*8];
#pragma unroll
    for (int oc = 0; oc < NOC; ++oc) {
      half8v b = *(const half8v*)&wt[(oc*16 + ln)*72 + kc*32 + quad*8];
      acc[oc] = __builtin_amdgcn_mfma_f32_16x16x32_f16(a, b, acc[oc], 0, 0, 0);
    }
  }
}

__global__ __launch_bounds__(256) void mlp_kernel(
    const float* __restrict__ x,
    const float* __restrict__ W1, const float* __restrict__ b1,
    const float* __restrict__ W2, const float* __restrict__ b2,
    const float* __restrict__ W3, const float* __restrict__ b3,
    const float* __restrict__ Wih, const float* __restrict__ bih,
    const float* __restrict__ bhh, float* __restrict__ G1)
{
  __shared__ __align__(16) _Float16 xs[64*72];    // x k-slab; reused for z
  __shared__ __align__(16) _Float16 wt[128*72];   // weight k-slab
  __shared__ __align__(16) _Float16 act[64*136];  // activations (reused in place)
  const int tid  = threadIdx.x;
  const int w    = tid >> 6;
  const int lane = tid & 63;
  const int ln   = lane & 15;
  const int quad = lane >> 4;
  const int rA   = 16*w + ln;
  const int r0   = 16*w + quad*4;
  const int R0   = blockIdx.x * 64;
  f32x4 acc[8];

  // ---- layer 1: 256 -> 128, tanh (4 k-slabs of 64) ----
#pragma unroll
  for (int oc = 0; oc < 8; ++oc) acc[oc] = (f32x4)0.f;
  for (int kt = 0; kt < 4; ++kt) {
#pragma unroll
    for (int it = 0; it < 4; ++it) {
      int idx = tid + it*256;
      int r = idx >> 4, k4 = idx & 15;
      float4 v = *(const float4*)&x[(size_t)(R0 + r)*OBS + kt*64 + k4*4];
      half4v h = { (_Float16)v.x, (_Float16)v.y, (_Float16)v.z, (_Float16)v.w };
      *(half4v*)&xs[r*72 + k4*4] = h;
    }
    stage_w16<128, 256>(W1, kt*64, wt, tid);
    __syncthreads();
    mfma_slab<8, 72>(xs, wt, rA, ln, quad, acc);
    __syncthreads();
  }
#pragma unroll
  for (int oc = 0; oc < 8; ++oc) {
    int o = oc*16 + ln;
    float bv = b1[o];
#pragma unroll
    for (int r = 0; r < 4; ++r)
      act[(r0 + r)*136 + o] = (_Float16)tanhf(acc[oc][r] + bv);
  }

  // ---- layer 2: 128 -> 128, tanh ----
#pragma unroll
  for (int oc = 0; oc < 8; ++oc) acc[oc] = (f32x4)0.f;
  for (int kt = 0; kt < 2; ++kt) {
    stage_w16<128, 128>(W2, kt*64, wt, tid);
    __syncthreads();
    mfma_slab<8, 136>(act + kt*64, wt, rA, ln, quad, acc);
    __syncthreads();
  }
#pragma unroll
  for (int oc = 0; oc < 8; ++oc) {
    int o = oc*16 + ln;
    float bv = b2[o];
#pragma unroll
    for (int r = 0; r < 4; ++r)
      act[(r0 + r)*136 + o] = (_Float16)tanhf(acc[oc][r] + bv);
  }

  // ---- layer 3: 128 -> 64, linear -> z into xs buffer ----
#pragma unroll
  for (int oc = 0; oc < 4; ++oc) acc[oc] = (f32x4)0.f;
  for (int kt = 0; kt < 2; ++kt) {
    stage_w16<64, 128>(W3, kt*64, wt, tid);
    __syncthreads();
    mfma_slab<4, 136>(act + kt*64, wt, rA, ln, quad, acc);
    __syncthreads();
  }
#pragma unroll
  for (int oc = 0; oc < 4; ++oc) {
    int o = oc*16 + ln;
    float bv = b3[o];
#pragma unroll
    for (int r = 0; r < 4; ++r)
      xs[(r0 + r)*72 + o] = (_Float16)(acc[oc][r] + bv);
  }

  // ---- layer 4: z(64) -> 128 gate inputs: z@Wih' + bih + bhh ----
#pragma unroll
  for (int oc = 0; oc < 8; ++oc) acc[oc] = (f32x4)0.f;
  stage_w16<128, 64>(Wih, 0, wt, tid);
  __syncthreads();
  mfma_slab<8, 72>(xs, wt, rA, ln, quad, acc);
#pragma unroll
  for (int oc = 0; oc < 8; ++oc) {
    int o = oc*16 + ln;
    float badd = bih[o] + bhh[o];
#pragma unroll
    for (int r = 0; r < 4; ++r)
      G1[(size_t)(R0 + r0 + r)*128 + o] = acc[oc][r] + badd;
  }
}

// ---------------------------------------------------------------------------
// LSTM scan v2: 1 row per 64-lane wave, 512 blocks.
// Lane L computes gates L and L+64 (i/f half and g/o half): 64 FMA/step.
// u = L&31: lane u has i_u,g_u; lane u+32 has f_u,o_u -> shfl_xor(32) pairs
// them for the c/h update (done on lanes<32; upper-lane results unused).
// done masks preloaded to LDS once, register-prefetched one step ahead.
// G1 gate inputs prefetched one step ahead. Fast tanh/sigmoid (no libm).
// ---------------------------------------------------------------------------
__global__ __launch_bounds__(64) void lstm_kernel(
    const float* __restrict__ G1, const float* __restrict__ Whh,
    const int* __restrict__ done, const float* __restrict__ h0,
    const float* __restrict__ c0, float* __restrict__ Y)
{
  __shared__ __align__(16) float hs[32];
  __shared__ float md[Tn];
  const int lane = threadIdx.x;        // 0..63
  const int u = lane & 31;
  const int row = blockIdx.x;          // 0..511
  const int b = row >> 5;

  float4 wlo[8], whi[8];               // Whh rows for gates (lane), (lane+64)
#pragma unroll
  for (int k4 = 0; k4 < 8; ++k4) {
    wlo[k4] = *(const float4*)&Whh[lane*HID + k4*4];
    whi[k4] = *(const float4*)&Whh[(64 + lane)*HID + k4*4];
  }
  md[lane]      = 1.f - (float)done[lane*Bn + b];
  md[lane + 64] = 1.f - (float)done[(lane + 64)*Bn + b];
  float h = h0[row*HID + u];
  float c = c0[row*HID + u];
  __syncthreads();

  const float* g0p = G1 + (size_t)row*128;
  float gln = g0p[lane], ghn = g0p[64 + lane];
  float mn = md[0];

  for (int t = 0; t < Tn; ++t) {
    float m = mn, gl = gln, gh = ghn;
    if (t < Tn - 1) {                  // prefetch next step (off critical path)
      mn = md[t + 1];
      const float* gq = G1 + ((size_t)(t + 1)*BA + row)*128;
      gln = gq[lane]; ghn = gq[64 + lane];
    }
    h *= m; c *= m;
    if (lane < 32) hs[u] = h;
    __syncthreads();                   // single wave: compiles to waitcnt only
#pragma unroll
    for (int k4 = 0; k4 < 8; ++k4) {
      float4 hv = *(const float4*)&hs[k4*4];   // broadcast read, conflict-free
      gl = fmaf(wlo[k4].x, hv.x, gl); gl = fmaf(wlo[k4].y, hv.y, gl);
      gl = fmaf(wlo[k4].z, hv.z, gl); gl = fmaf(wlo[k4].w, hv.w, gl);
      gh = fmaf(whi[k4].x, hv.x, gh); gh = fmaf(whi[k4].y, hv.y, gh);
      gh = fmaf(whi[k4].z, hv.z, gh); gh = fmaf(whi[k4].w, hv.w, gh);
    }
    float slo = fast_sig(gl);          // lanes<32: i_u ; lanes>=32: f_u
    float th  = fast_tanh(gh);
    float sh  = fast_sig(gh);
    float ahi = (lane < 32) ? th : sh; // lanes<32: g_u ; lanes>=32: o_u
    float fv = __shfl_xor(slo, 32);    // lanes<32 receive f_u
    float ov = __shfl_xor(ahi, 32);    // lanes<32 receive o_u
    c = fmaf(fv, c, slo * ahi);        // valid on lanes<32
    h = ov * fast_tanh(c);
    if (lane < 32) Y[((size_t)t*BA + row)*HID + u] = h;
  }
}

// ---------------------------------------------------------------------------
// Heads: per row, 27 logits (3 heads x 9), log-softmax, entropy, gather,
// product of chosen log-probs. One thread per row; y staged in LDS (+1 pad).
// ---------------------------------------------------------------------------
__global__ __launch_bounds__(256) void head_kernel(
    const float* __restrict__ Y, const float* __restrict__ Wh,
    const float* __restrict__ bh, const int* __restrict__ actions,
    float* __restrict__ out)
{
  __shared__ float ys[256*33];
  __shared__ __align__(16) float whs[27*32];
  __shared__ float bhs[32];
  const int tid = threadIdx.x;
  const int R0 = blockIdx.x * 256;
  for (int i = tid; i < 27*32; i += 256) whs[i] = Wh[i];
  if (tid < 27) bhs[tid] = bh[tid];
#pragma unroll
  for (int it = 0; it < 8; ++it) {
    int idx = tid + it*256;
    int r = idx >> 3, f4 = idx & 7;
    float4 v = *(const float4*)&Y[(size_t)(R0 + r)*32 + f4*4];
    ys[r*33 + f4*4 + 0] = v.x;
    ys[r*33 + f4*4 + 1] = v.y;
    ys[r*33 + f4*4 + 2] = v.z;
    ys[r*33 + f4*4 + 3] = v.w;
  }
  __syncthreads();
  float yv[32];
#pragma unroll
  for (int k = 0; k < 32; ++k) yv[k] = ys[tid*33 + k];
  float l[27];
#pragma unroll
  for (int m = 0; m < 27; ++m) {
    float a = bhs[m];
#pragma unroll
    for (int k4 = 0; k4 < 8; ++k4) {
      float4 w4 = *(const float4*)&whs[m*32 + k4*4];   // uniform -> broadcast
      a = fmaf(yv[k4*4+0], w4.x, a);
      a = fmaf(yv[k4*4+1], w4.y, a);
      a = fmaf(yv[k4*4+2], w4.z, a);
      a = fmaf(yv[k4*4+3], w4.w, a);
    }
    l[m] = a;
  }
  const int row = R0 + tid;
  float logprob = 1.0f;
#pragma unroll
  for (int kk = 0; kk < 3; ++kk) {
    float mx = l[kk*9];
#pragma unroll
    for (int n = 1; n < 9; ++n) mx = fmaxf(mx, l[kk*9+n]);
    float s = 0.f;
#pragma unroll
    for (int n = 0; n < 9; ++n) s += __expf(l[kk*9+n] - mx);
    float lse = mx + __logf(s);
    float ent = 0.f;
#pragma unroll
    for (int n = 0; n < 9; ++n) {
      float lp = l[kk*9+n] - lse;
      ent -= __expf(lp) * lp;
    }
    int a = actions[row*3 + kk];
    float alp = 0.f;
#pragma unroll
    for (int n = 0; n < 9; ++n) alp = (a == n) ? (l[kk*9+n] - lse) : alp;
    logprob *= alp;
    out[row*3 + kk] = (float)a;          // actions echoed as float
    out[OUT_ENT + row*3 + kk] = ent;
  }
  out[OUT_LP + row] = logprob;
}

extern "C" void kernel_launch(void* const* d_in, const int* in_sizes, int n_in,
                              void* d_out, int out_size, void* d_ws, size_t ws_size,
                              hipStream_t stream)
{
  const float* x       = (const float*)d_in[0];
  const int*   done    = (const int*)  d_in[1];
  const int*   actions = (const int*)  d_in[2];
  const float* W1  = (const float*)d_in[3];
  const float* b1  = (const float*)d_in[4];
  const float* W2  = (const float*)d_in[5];
  const float* b2  = (const float*)d_in[6];
  const float* W3  = (const float*)d_in[7];
  const float* b3  = (const float*)d_in[8];
  const float* Wih = (const float*)d_in[9];
  const float* Whh = (const float*)d_in[10];
  const float* bih = (const float*)d_in[11];
  const float* bhh = (const float*)d_in[12];
  const float* Wh  = (const float*)d_in[13];
  const float* bh  = (const float*)d_in[14];
  const float* h0  = (const float*)d_in[15];
  const float* c0  = (const float*)d_in[16];
  float* out = (float*)d_out;

  float* G1 = (float*)d_ws;                    // [65536][128] = 33.5 MB
  float* Y  = G1 + (size_t)TBA * 128;          // [65536][32]  =  8.4 MB

  mlp_kernel<<<TBA/64, 256, 0, stream>>>(x, W1, b1, W2, b2, W3, b3,
                                         Wih, bih, bhh, G1);
  lstm_kernel<<<BA, 64, 0, stream>>>(G1, Whh, done, h0, c0, Y);
  head_kernel<<<TBA/256, 256, 0, stream>>>(Y, Wh, bh, actions, out);
}